// Round 12
// baseline (138.135 us; speedup 1.0000x reference)
//
#include <hip/hip_runtime.h>
#include <hip/hip_bf16.h>
#include <math.h>

#define NN 4096
#define DD 127
#define HH 128
#define OUTD 3
#define NTYPES 6
#define SIM_THRESH 0.9f
#define BN_EPS 1e-5f
#define MROW 4    // rows per block in build_mask
#define NREP 8    // accumulator replicas
#define GL_STRIDE 512  // CSR row stride; cross-degree ~ Binom(3413,.05): 26-sigma

typedef unsigned short ushortT;
typedef __attribute__((ext_vector_type(8))) short short8;   // 8 bf16 (4 VGPRs)
typedef __attribute__((ext_vector_type(4))) float f32x4;

// round-to-nearest-even fp32 -> bf16 (bit pattern)
static __device__ inline ushortT f2bf(float f) {
    unsigned u = __float_as_uint(f);
    unsigned r = (u + 0x7fffu + ((u >> 16) & 1u)) >> 16;
    return (ushortT)r;
}
static __device__ inline float bf2f(ushortT b) {
    return __uint_as_float(((unsigned)b) << 16);
}

// ---------------------------------------------------------------------------
// Kernel P v5: blocks 0..7 convert W to bf16 (row-major — MFMA B fragment
// reads k-contiguous). Blocks 8..263: 16-row strips -> xbf (bf16 only; fp32
// x dropped entirely), fn, histogram, S0 type-sums (NREP replicas, from bf16).
// ---------------------------------------------------------------------------
__global__ __launch_bounds__(256) void prep(
    const float* __restrict__ x_now, const int* __restrict__ sat,
    const float* __restrict__ Wl, const float* __restrict__ Wr,
    ushortT* __restrict__ Wbf, ushortT* __restrict__ xbf,
    float4* __restrict__ fn, int* __restrict__ cnt,
    float* __restrict__ S0rep)
{
    int t = threadIdx.x;
    if (blockIdx.x < 8) {
        int baseidx = blockIdx.x * 8192;
        #pragma unroll
        for (int it = 0; it < 32; ++it) {
            int idx = baseidx + it * 256 + t;
            float v = (idx < 32768) ? Wl[idx] : Wr[idx - 32768];
            Wbf[idx] = f2bf(v);
        }
        return;
    }

    int sb = blockIdx.x - 8;           // strip 0..255
    int base = sb * 16;
    int rep = sb & (NREP - 1);
    __shared__ int stypes[16];
    int myti = -1;
    if (t < 16) {
        int row = base + t;
        int ti = sat[row]; ti = min(max(ti, 0), NTYPES - 1);
        stypes[t] = ti; myti = ti;
        const float* rp = x_now + (size_t)row * DD;
        float f0 = rp[0], f2 = rp[1], f3 = rp[2];
        float nrm = fmaxf(sqrtf(2.f * f0 * f0 + f2 * f2 + f3 * f3), 1e-12f);
        float inv = 1.f / nrm;
        fn[row] = make_float4(f0 * inv, f0 * inv, f2 * inv, f3 * inv);
    }
    #pragma unroll
    for (int it = 0; it < 8; ++it) {
        int lin = it * 256 + t;        // 0..2047
        int rl = lin >> 7, col = lin & 127;
        int row = base + rl;
        const float* rp = x_now + (size_t)row * DD;
        float v = (col == 0) ? rp[0] : rp[col - 1];
        xbf[(size_t)row * HH + col] = f2bf(v);
    }
    __syncthreads();
    if (t < 64) {
        #pragma unroll
        for (int tt = 0; tt < NTYPES; ++tt) {
            unsigned long long m = __ballot(myti == tt);
            if (t == 0) {
                int c = __popcll(m);
                if (c) atomicAdd(&cnt[rep * NTYPES + tt], c);
            }
        }
    }
    if (t < 128) {
        float acc[NTYPES] = {0.f, 0.f, 0.f, 0.f, 0.f, 0.f};
        for (int r = 0; r < 16; ++r) {
            float v = bf2f(xbf[(size_t)(base + r) * HH + t]);
            int tt = stypes[r];
            #pragma unroll
            for (int q = 0; q < NTYPES; ++q) acc[q] += (tt == q) ? v : 0.f;
        }
        #pragma unroll
        for (int q = 0; q < NTYPES; ++q)
            atomicAdd(&S0rep[(rep * NTYPES + q) * HH + t], acc[q]);
    }
}

// ---------------------------------------------------------------------------
// Kernel B v4: cosine adjacency -> CSR list (decode ONCE, here; gathers no
// longer scan/ffs). b-loop split across two thread-halves as v3. 128-thread
// exclusive scan for per-row offsets; Glist row stride GL_STRIDE.
// ---------------------------------------------------------------------------
__global__ __launch_bounds__(256) void build_mask(
    const float4* __restrict__ fn, const int* __restrict__ sat,
    const int* __restrict__ cnt, ushortT* __restrict__ Glist,
    int* __restrict__ ncross, float* __restrict__ deg)
{
    int i0 = blockIdx.x * MROW;
    int t = threadIdx.x;
    int w = t & 127;
    int half = t >> 7;
    float4 fi[MROW];
    int ti[MROW];
    #pragma unroll
    for (int r = 0; r < MROW; ++r) {
        fi[r] = fn[i0 + r];
        int tt = sat[i0 + r];
        ti[r] = min(max(tt, 0), NTYPES - 1);
    }
    unsigned word[MROW] = {0, 0, 0, 0};
    int bbase = half * 16;
    for (int bb = 0; bb < 16; ++bb) {
        int b = bbase + bb;
        int j = b * 128 + w;
        float4 fj = fn[j];
        int tj = sat[j];
        #pragma unroll
        for (int r = 0; r < MROW; ++r) {
            float dot = fi[r].x * fj.x + fi[r].y * fj.y
                      + fi[r].z * fj.z + fi[r].w * fj.w;
            if (tj != ti[r] && dot > SIM_THRESH) word[r] |= (1u << b);
        }
    }
    __shared__ unsigned wpart[MROW][128];
    if (half == 1) {
        #pragma unroll
        for (int r = 0; r < MROW; ++r) wpart[r][w] = word[r];
    }
    __syncthreads();
    __shared__ int wt[2][MROW];
    unsigned full[MROW];
    int pcs[MROW], xin[MROW];
    int lane = w & 63, wv2 = w >> 6;
    if (half == 0) {
        #pragma unroll
        for (int r = 0; r < MROW; ++r) {
            full[r] = word[r] | wpart[r][w];
            pcs[r] = __popc(full[r]);
            xin[r] = pcs[r];
        }
        for (int s = 1; s < 64; s <<= 1) {
            #pragma unroll
            for (int r = 0; r < MROW; ++r) {
                int v = __shfl_up(xin[r], s);
                if (lane >= s) xin[r] += v;
            }
        }
        if (lane == 63) {
            #pragma unroll
            for (int r = 0; r < MROW; ++r) wt[wv2][r] = xin[r];
        }
    }
    __syncthreads();
    if (half == 0) {
        #pragma unroll
        for (int r = 0; r < MROW; ++r) {
            int excl = xin[r] - pcs[r] + (wv2 ? wt[0][r] : 0);
            int ofs = (i0 + r) * GL_STRIDE + excl;
            unsigned ww = full[r];
            while (ww) {
                int b = __ffs(ww) - 1; ww &= ww - 1;
                Glist[ofs++] = (ushortT)(b * 128 + w);
            }
        }
    }
    if (t < MROW) {
        int r = t;
        int total = wt[0][r] + wt[1][r];
        ncross[i0 + r] = total;
        int ctot = 0;
        #pragma unroll
        for (int rr = 0; rr < NREP; ++rr) ctot += cnt[rr * NTYPES + ti[r]];
        deg[i0 + r] = fmaxf((float)(ctot - 1 + total), 1.0f);
    }
}

// ---------------------------------------------------------------------------
// Kernel G v2 (decode-free gather): two waves per row; wave (r,hf) stages
// its half of the precomputed CSR list (coalesced) into LDS, then gathers
// bf16 rows 4-per-instruction. No scan, no ffs, no mask loads. Own-row and
// m all via bf16; m written bf16 for the MFMA GEMM.
// ---------------------------------------------------------------------------
__global__ __launch_bounds__(256, 8) void gather_kernel(
    const ushortT* __restrict__ hbf, const ushortT* __restrict__ Glist,
    const int* __restrict__ ncross, const float* __restrict__ deg,
    const float* __restrict__ S, const int* __restrict__ sat,
    ushortT* __restrict__ mbf)
{
    int t = threadIdx.x;
    int wv = t >> 6, lane = t & 63;
    int r = wv >> 1, hf = wv & 1;
    int i0 = blockIdx.x * 2;
    int i = i0 + r;

    __shared__ ushortT idx[4][256];                      // 2 KB
    __shared__ __align__(16) float part[4][HH];          // 2 KB
    __shared__ int tarr[2];

    if (t < 2) {
        int tt = sat[i0 + t];
        tarr[t] = min(max(tt, 0), NTYPES - 1);
    }

    int n = ncross[i];
    int hcnt = (n + 1) >> 1;
    int start = hf ? hcnt : 0;
    int mycount = hf ? (n - hcnt) : hcnt;
    const ushortT* gl = Glist + (size_t)i * GL_STRIDE + start;
    #pragma unroll
    for (int b = 0; b < 4; ++b) {
        int ii = b * 64 + lane;
        if (ii < mycount) idx[wv][ii] = gl[ii];          // coalesced
    }

    int q = lane >> 4;        // 0..3 neighbor slot
    int c = lane & 15;        // 0..15 -> columns 8c..8c+7
    const uint4* __restrict__ hb4 = (const uint4*)hbf;
    float acc[8] = {0.f, 0.f, 0.f, 0.f, 0.f, 0.f, 0.f, 0.f};
#define BFACC(vv)                                                         \
    {                                                                     \
        acc[0] += __uint_as_float((vv).x << 16);                          \
        acc[1] += __uint_as_float((vv).x & 0xffff0000u);                  \
        acc[2] += __uint_as_float((vv).y << 16);                          \
        acc[3] += __uint_as_float((vv).y & 0xffff0000u);                  \
        acc[4] += __uint_as_float((vv).z << 16);                          \
        acc[5] += __uint_as_float((vv).z & 0xffff0000u);                  \
        acc[6] += __uint_as_float((vv).w << 16);                          \
        acc[7] += __uint_as_float((vv).w & 0xffff0000u);                  \
    }
    int g = 0;
    for (; g + 24 <= mycount; g += 24) {
        int j0 = idx[wv][g + q];
        int j1 = idx[wv][g + 4 + q];
        int j2 = idx[wv][g + 8 + q];
        int j3 = idx[wv][g + 12 + q];
        int j4 = idx[wv][g + 16 + q];
        int j5 = idx[wv][g + 20 + q];
        uint4 v0 = hb4[j0 * 16 + c];
        uint4 v1 = hb4[j1 * 16 + c];
        uint4 v2 = hb4[j2 * 16 + c];
        uint4 v3 = hb4[j3 * 16 + c];
        uint4 v4 = hb4[j4 * 16 + c];
        uint4 v5 = hb4[j5 * 16 + c];
        BFACC(v0); BFACC(v1); BFACC(v2); BFACC(v3); BFACC(v4); BFACC(v5);
    }
    for (; g + 4 <= mycount; g += 4) {
        int j0 = idx[wv][g + q];
        uint4 v0 = hb4[j0 * 16 + c];
        BFACC(v0);
    }
    if (q < mycount - g) {
        int j0 = idx[wv][g + q];
        uint4 v0 = hb4[j0 * 16 + c];
        BFACC(v0);
    }
#undef BFACC
    #pragma unroll
    for (int d = 0; d < 8; ++d) {
        acc[d] += __shfl_down(acc[d], 32);
        acc[d] += __shfl_down(acc[d], 16);
    }
    if (lane < 16) {
        float4 p0 = {acc[0], acc[1], acc[2], acc[3]};
        float4 p1 = {acc[4], acc[5], acc[6], acc[7]};
        ((float4*)part[wv])[c * 2] = p0;
        ((float4*)part[wv])[c * 2 + 1] = p1;
    }
    __syncthreads();   // partials + tarr ready

    if (hf == 0 && lane < 32) {
        int cc = lane;
        float4 p0 = ((const float4*)part[wv])[cc];
        float4 p1 = ((const float4*)part[wv + 1])[cc];
        int ti = tarr[r];
        float rdeg = 1.f / deg[i];
        uint2 hu = ((const uint2*)(hbf + (size_t)i * HH))[cc];
        float4 hv;
        hv.x = __uint_as_float(hu.x << 16);
        hv.y = __uint_as_float(hu.x & 0xffff0000u);
        hv.z = __uint_as_float(hu.y << 16);
        hv.w = __uint_as_float(hu.y & 0xffff0000u);
        float4 Sv = {0.f, 0.f, 0.f, 0.f};
        #pragma unroll
        for (int rr = 0; rr < NREP; ++rr) {
            float4 sv = ((const float4*)S)[(rr * NTYPES + ti) * 32 + cc];
            Sv.x += sv.x; Sv.y += sv.y; Sv.z += sv.z; Sv.w += sv.w;
        }
        float4 m;
        m.x = (Sv.x - hv.x + p0.x + p1.x) * rdeg;
        m.y = (Sv.y - hv.y + p0.y + p1.y) * rdeg;
        m.z = (Sv.z - hv.z + p0.z + p1.z) * rdeg;
        m.w = (Sv.w - hv.w + p0.w + p1.w) * rdeg;
        ushort4 mb;
        mb.x = f2bf(m.x); mb.y = f2bf(m.y);
        mb.z = f2bf(m.z); mb.w = f2bf(m.w);
        ((ushort4*)(mbf + (size_t)i * HH))[cc] = mb;
    }
}

// ---------------------------------------------------------------------------
// Kernel M (MFMA GEMM): h_next = relu([mbf | hbf] @ [Wl | Wr]^T + bl).
// 256 blocks x 16 rows, K=256, bf16 16x16x32 MFMA; W read row-major as the
// B fragment. D layout col=lane&15, row=quad*4+reg (m89-verified).
// MODE 1: writes h1 bf16 only + next-layer type sums.
// MODE 2: writes h2 fp32 + BN stats.
// ---------------------------------------------------------------------------
template <int MODE>
__global__ __launch_bounds__(256) void gemm_kernel(
    const ushortT* __restrict__ mbf, const ushortT* __restrict__ hbf,
    const ushortT* __restrict__ Wlbf, const ushortT* __restrict__ Wrbf,
    const float* __restrict__ bl, const int* __restrict__ sat,
    float* __restrict__ hout, ushortT* __restrict__ houtbf,
    float* __restrict__ acc0, float* __restrict__ acc1)
{
    int t = threadIdx.x;
    int wv = t >> 6, lane = t & 63;
    int p = lane & 15, q = lane >> 4;
    int i0 = blockIdx.x * 16;

    __shared__ float sh[16][129];
    __shared__ int stypes[16];
    if (t < 16) {
        int tt = sat[i0 + t];
        stypes[t] = min(max(tt, 0), NTYPES - 1);
    }

    const ushortT* arow_m = mbf + (size_t)(i0 + p) * HH + q * 8;
    const ushortT* arow_h = hbf + (size_t)(i0 + p) * HH + q * 8;
    short8 am[4], ah[4];
    #pragma unroll
    for (int s = 0; s < 4; ++s) {
        am[s] = *(const short8*)(arow_m + s * 32);
        ah[s] = *(const short8*)(arow_h + s * 32);
    }

    #pragma unroll
    for (int nt = 0; nt < 2; ++nt) {
        int n0 = (wv * 2 + nt) * 16;
        const ushortT* brow_l = Wlbf + (size_t)(n0 + p) * HH + q * 8;
        const ushortT* brow_r = Wrbf + (size_t)(n0 + p) * HH + q * 8;
        f32x4 acc = {0.f, 0.f, 0.f, 0.f};
        #pragma unroll
        for (int s = 0; s < 4; ++s) {
            short8 b = *(const short8*)(brow_l + s * 32);
            acc = __builtin_amdgcn_mfma_f32_16x16x32_bf16(am[s], b, acc, 0, 0, 0);
        }
        #pragma unroll
        for (int s = 0; s < 4; ++s) {
            short8 b = *(const short8*)(brow_r + s * 32);
            acc = __builtin_amdgcn_mfma_f32_16x16x32_bf16(ah[s], b, acc, 0, 0, 0);
        }
        int o = n0 + p;
        float bv = bl[o];
        #pragma unroll
        for (int rg = 0; rg < 4; ++rg) {
            float v = fmaxf(acc[rg] + bv, 0.f);
            sh[q * 4 + rg][o] = v;
        }
    }
    __syncthreads();

    #pragma unroll
    for (int e = 0; e < 8; ++e) {
        int lin = e * 256 + t;
        int rr = lin >> 7, cc = lin & 127;
        float v = sh[rr][cc];
        if (MODE == 1) houtbf[(size_t)i0 * HH + lin] = f2bf(v);
        else          hout[(size_t)i0 * HH + lin] = v;
    }
    int rep = blockIdx.x & (NREP - 1);
    if (t < HH) {
        if (MODE == 1) {
            float accq[NTYPES] = {0.f, 0.f, 0.f, 0.f, 0.f, 0.f};
            for (int r = 0; r < 16; ++r) {
                float v = sh[r][t];
                int tt = stypes[r];
                #pragma unroll
                for (int qq = 0; qq < NTYPES; ++qq)
                    accq[qq] += (tt == qq) ? v : 0.f;
            }
            #pragma unroll
            for (int qq = 0; qq < NTYPES; ++qq)
                atomicAdd(&acc0[(rep * NTYPES + qq) * HH + t], accq[qq]);
        } else {
            float s = 0.f, s2 = 0.f;
            for (int r = 0; r < 16; ++r) {
                float v = sh[r][t];
                s += v; s2 += v * v;
            }
            atomicAdd(&acc0[rep * HH + t], s);
            atomicAdd(&acc1[rep * HH + t], s2);
        }
    }
}

// ---------------------------------------------------------------------------
// Kernel F: BN apply + head, one wave per row; sums the NREP stat replicas.
// ---------------------------------------------------------------------------
__global__ __launch_bounds__(256) void finalize(
    const float* __restrict__ h, const float* __restrict__ musum8,
    const float* __restrict__ varsum8, const float* __restrict__ gamma,
    const float* __restrict__ beta, const float* __restrict__ Wo,
    const float* __restrict__ bo, float* __restrict__ out_h,
    float* __restrict__ out_o)
{
    int t = threadIdx.x;
    int wv = t >> 6;
    int lane = t & 63;
    int i = blockIdx.x * 4 + wv;

    float2 mus = {0.f, 0.f}, vas = {0.f, 0.f};
    #pragma unroll
    for (int r = 0; r < NREP; ++r) {
        float2 a = ((const float2*)(musum8 + r * HH))[lane];
        float2 b = ((const float2*)(varsum8 + r * HH))[lane];
        mus.x += a.x; mus.y += a.y;
        vas.x += b.x; vas.y += b.y;
    }
    float2 ga  = ((const float2*)gamma)[lane];
    float2 be  = ((const float2*)beta)[lane];
    float mu0 = mus.x * (1.f / NN), mu1 = mus.y * (1.f / NN);
    float v0 = vas.x * (1.f / NN) - mu0 * mu0;
    float v1 = vas.y * (1.f / NN) - mu1 * mu1;
    float sc0 = ga.x / sqrtf(v0 + BN_EPS), sc1 = ga.y / sqrtf(v1 + BN_EPS);
    float sh0 = be.x - mu0 * sc0, sh1 = be.y - mu1 * sc1;

    float2 hv = ((const float2*)(h + (size_t)i * HH))[lane];
    float2 hb;
    hb.x = hv.x * sc0 + sh0;
    hb.y = hv.y * sc1 + sh1;
    ((float2*)(out_h + (size_t)i * HH))[lane] = hb;

    float2 w0 = ((const float2*)Wo)[lane];
    float2 w1 = ((const float2*)(Wo + HH))[lane];
    float2 w2 = ((const float2*)(Wo + 2 * HH))[lane];
    float p0 = hb.x * w0.x + hb.y * w0.y;
    float p1 = hb.x * w1.x + hb.y * w1.y;
    float p2 = hb.x * w2.x + hb.y * w2.y;
    for (int s = 32; s; s >>= 1) {
        p0 += __shfl_down(p0, s);
        p1 += __shfl_down(p1, s);
        p2 += __shfl_down(p2, s);
    }
    if (lane == 0) {
        out_o[(size_t)i * OUTD + 0] = p0 + bo[0];
        out_o[(size_t)i * OUTD + 1] = p1 + bo[1];
        out_o[(size_t)i * OUTD + 2] = p2 + bo[2];
    }
}

// ---------------------------------------------------------------------------
extern "C" void kernel_launch(void* const* d_in, const int* in_sizes, int n_in,
                              void* d_out, int out_size, void* d_ws, size_t ws_size,
                              hipStream_t stream)
{
    (void)in_sizes; (void)n_in; (void)out_size; (void)ws_size;
    const float* x_now = (const float*)d_in[0];
    const int*   sat   = (const int*)d_in[1];
    const float* Wl    = (const float*)d_in[2];
    const float* bl    = (const float*)d_in[3];
    const float* Wr    = (const float*)d_in[4];
    const float* gamma = (const float*)d_in[5];
    const float* beta  = (const float*)d_in[6];
    const float* Wo    = (const float*)d_in[7];
    const float* bo    = (const float*)d_in[8];

    float* ws = (float*)d_ws;
    float*  h2     = ws;                              // NN*HH f
    float4* fn     = (float4*)(h2 + (size_t)NN * HH); // NN float4
    float*  deg    = (float*)(fn + NN);               // NN
    int*    ncross = (int*)(deg + NN);                // NN
    // ---- zeroed accumulator region (one contiguous memset) ----
    int*    cnt    = ncross + NN;                     // 64
    float*  S0rep  = (float*)(cnt + 64);              // 6144
    float*  S1rep  = S0rep + NREP * NTYPES * HH;      // 6144
    float*  mu8    = S1rep + NREP * NTYPES * HH;      // 1024
    float*  var8   = mu8 + NREP * HH;                 // 1024
    // ---- bf16 region ----
    ushortT* Wbf   = (ushortT*)(var8 + NREP * HH);    // 65536 us
    ushortT* x0bf  = Wbf + 65536;                     // NN*HH us
    ushortT* h1bf  = x0bf + (size_t)NN * HH;          // NN*HH us
    ushortT* mbf   = h1bf + (size_t)NN * HH;          // NN*HH us
    ushortT* Glist = mbf + (size_t)NN * HH;           // NN*GL_STRIDE us

    size_t zero_bytes = (64 + 2 * NREP * NTYPES * HH + 2 * NREP * HH)
                        * sizeof(float);
    hipMemsetAsync(cnt, 0, zero_bytes, stream);

    prep<<<264, 256, 0, stream>>>(x_now, sat, Wl, Wr, Wbf, x0bf, fn, cnt,
                                  S0rep);
    build_mask<<<NN / MROW, 256, 0, stream>>>(fn, sat, cnt, Glist, ncross, deg);

    // layer 1
    gather_kernel<<<NN / 2, 256, 0, stream>>>(x0bf, Glist, ncross, deg, S0rep,
                                              sat, mbf);
    gemm_kernel<1><<<NN / 16, 256, 0, stream>>>(
        mbf, x0bf, Wbf, Wbf + 32768, bl, sat, nullptr, h1bf, S1rep, nullptr);

    // layer 2
    gather_kernel<<<NN / 2, 256, 0, stream>>>(h1bf, Glist, ncross, deg, S1rep,
                                              sat, mbf);
    gemm_kernel<2><<<NN / 16, 256, 0, stream>>>(
        mbf, h1bf, Wbf + 16384, Wbf + 49152, bl + HH, sat, h2, nullptr,
        mu8, var8);

    finalize<<<NN / 4, 256, 0, stream>>>(h2, mu8, var8, gamma, beta, Wo, bo,
                                         (float*)d_out, (float*)d_out + (size_t)NN * HH);
}